// Round 7
// baseline (424.823 us; speedup 1.0000x reference)
//
#include <hip/hip_runtime.h>
#include <stdint.h>

typedef __attribute__((ext_vector_type(4))) int int4v;
typedef __attribute__((ext_vector_type(16))) int int16v;
typedef __attribute__((ext_vector_type(4))) uint32_t uint4v;

#define M_DIM 8192
#define N_DIM 4096
#define K_DIM 4096

// K-permuted layout: within each 64-byte K chunk, stored byte p holds
// original k = (p>>2) + 16*(p&3). Applied identically to A and B => MFMA
// dot products unchanged. GEMM XOR-swizzles 16-B chunks within each 128-B
// LDS row (slot = chunk ^ (row&7)), applied at the global source address
// during staging, inverted at fragment-read.
//
// R6: barrier-free pipelined K-loop. Double-buffered LDS; cross-wave sync
// via LDS atomic generation counters (acquire spins / release adds) so
// global_load_lds DMAs stay in flight across tile boundaries instead of
// being drained at a __syncthreads vmcnt(0) every iteration (the m97
// plateau). Explicit vmcnt(0) happens only AFTER a full MFMA block.

// ---------------- pack x: int32 -> int8, K-permuted ----------------
__global__ void pack_a_perm(const int* __restrict__ x, uint4v* __restrict__ a8) {
    const int g = blockIdx.x * blockDim.x + threadIdx.x;
    const int w0 = (g & 3) * 4;
    const int chunk = g >> 2;
    const int* base = x + (size_t)chunk * 64;
    int4v L[4];
#pragma unroll
    for (int j = 0; j < 4; ++j) L[j] = *(const int4v*)(base + j * 16 + w0);
    uint4v outv;
#pragma unroll
    for (int wi = 0; wi < 4; ++wi) {
        outv[wi] = (uint32_t)(L[0][wi] & 0xff) | ((uint32_t)(L[1][wi] & 0xff) << 8) |
                   ((uint32_t)(L[2][wi] & 0xff) << 16) | ((uint32_t)(L[3][wi] & 0xff) << 24);
    }
    a8[g] = outv;
}

// ------- transpose+pack weight: [K][N] int32 -> Bt[N][K-permuted] int8 -------
__global__ void transpose_b_perm(const int* __restrict__ w, int8_t* __restrict__ bt) {
    const int t = threadIdx.x;
    const int kt = blockIdx.y * 64;
    const int n0 = blockIdx.x * 64;
    const int c4 = t & 3;
    const int n = t >> 2;
    const int w0 = c4 * 4;
    const int* col = w + (size_t)kt * N_DIM + n0 + n;
    uint4v outv;
#pragma unroll
    for (int wi = 0; wi < 4; ++wi) {
        uint32_t p = 0;
#pragma unroll
        for (int j = 0; j < 4; ++j) {
            uint32_t b = (uint32_t)(col[(size_t)(w0 + wi + 16 * j) * N_DIM] & 0xff);
            p |= b << (8 * j);
        }
        outv[wi] = p;
    }
    *(uint4v*)&bt[(size_t)(n0 + n) * K_DIM + kt + w0 * 4] = outv;
}

// ---- GEMM: 128x128 block, 64x64 wave, BK=128, dbuf + flag-pipelined ----
__device__ inline void async16(const void* g, void* l) {
    __builtin_amdgcn_global_load_lds(
        (const __attribute__((address_space(1))) uint32_t*)g,
        (__attribute__((address_space(3))) uint32_t*)l, 16, 0, 0);
}

__device__ __forceinline__ void wait_ge(uint32_t* f, uint32_t tgt) {
    while (__hip_atomic_load(f, __ATOMIC_ACQUIRE, __HIP_MEMORY_SCOPE_WORKGROUP) < tgt) {}
}

__global__ void __launch_bounds__(256, 2)
gemm_kernel(const int8_t* __restrict__ A, const int8_t* __restrict__ Bt,
            const float* __restrict__ pa, const float* __restrict__ pb,
            int* __restrict__ out) {
    __shared__ int8_t smem[65536 + 64];
    // buffers: A[p] at p*16384, B[p] at 32768 + p*16384
    uint32_t* flags = (uint32_t*)(smem + 65536);  // [0..1]=staged, [2..3]=freed

    const int t = threadIdx.x;
    const int lane = t & 63;
    const int wave = t >> 6;
    const int m0 = blockIdx.y * 128;
    const int n0 = blockIdx.x * 128;
    const int wm = (wave >> 1) * 64;
    const int wn = (wave & 1) * 64;

    if (t < 4) flags[t] = 0;
    __syncthreads();  // once, before any flag use

    int16v acc[2][2];
#pragma unroll
    for (int i = 0; i < 2; ++i)
#pragma unroll
        for (int j = 0; j < 2; ++j)
#pragma unroll
            for (int r = 0; r < 16; ++r) acc[i][j][r] = 0;

    // staging addressing (row&7 == srow for all steps -> step-invariant swizzle)
    const int srow = lane >> 3;
    const int sslot = lane & 7;
    const uint32_t oStage = (uint32_t)(wave * 8 + srow) * K_DIM + ((sslot ^ srow) * 16);
    const uint32_t ldsStage = (uint32_t)(wave * 8) * 128;
    const int8_t* Ab = A + (size_t)m0 * K_DIM;
    const int8_t* Bb = Bt + (size_t)n0 * K_DIM;

    // fragment addressing
    const int l31 = lane & 31;
    const int fg = lane >> 5;
    const int c7 = l31 & 7;
    const uint32_t aoff = (uint32_t)(wm + l31) * 128;
    const uint32_t boff = (uint32_t)(wn + l31) * 128;

    const bool sig = (lane == 0);

    // prologue: stage tile 0 into buffer 0
#pragma unroll
    for (int s = 0; s < 4; ++s) {
        async16(Ab + oStage + s * (32 * K_DIM), smem + ldsStage + s * 4096);
        async16(Bb + oStage + s * (32 * K_DIM), smem + 32768 + ldsStage + s * 4096);
    }
    __builtin_amdgcn_s_waitcnt(0x0F70);  // vmcnt(0) only
    if (sig) __hip_atomic_fetch_add(&flags[0], 1u, __ATOMIC_RELEASE, __HIP_MEMORY_SCOPE_WORKGROUP);

    const int NT = K_DIM / 128;  // 32 tiles
#pragma unroll 2
    for (int tt = 0; tt < NT; ++tt) {
        const int p = tt & 1;
        const int q = p ^ 1;

        if (tt + 1 < NT) {
            // buffer q must be fully read by all waves (4*((tt+1)>>1) completions)
            wait_ge(&flags[2 + q], 4u * (uint32_t)((tt + 1) >> 1));
            const uint32_t koffs = (uint32_t)(tt + 1) * 128;
#pragma unroll
            for (int s = 0; s < 4; ++s) {
                async16(Ab + oStage + koffs + s * (32 * K_DIM),
                        smem + q * 16384 + ldsStage + s * 4096);
                async16(Bb + oStage + koffs + s * (32 * K_DIM),
                        smem + 32768 + q * 16384 + ldsStage + s * 4096);
            }
        }

        // tile tt fully staged?
        wait_ge(&flags[p], 4u * (uint32_t)((tt >> 1) + 1));

        const int8_t* Asp = smem + p * 16384;
        const int8_t* Bsp = smem + 32768 + p * 16384;
#pragma unroll
        for (int ks = 0; ks < 4; ++ks) {
            const uint32_t cs = (uint32_t)(((ks * 2 + fg) ^ c7) * 16);
            int4v af[2], bf[2];
#pragma unroll
            for (int i = 0; i < 2; ++i) {
                af[i] = *(const int4v*)&Asp[aoff + i * 4096 + cs];
                bf[i] = *(const int4v*)&Bsp[boff + i * 4096 + cs];
            }
#pragma unroll
            for (int i = 0; i < 2; ++i)
#pragma unroll
                for (int j = 0; j < 2; ++j)
                    acc[i][j] = __builtin_amdgcn_mfma_i32_32x32x32_i8(af[i], bf[j],
                                                                       acc[i][j], 0, 0, 0);
        }

        // signal: this wave finished reading buffer p
        if (sig) __hip_atomic_fetch_add(&flags[2 + p], 1u, __ATOMIC_RELEASE, __HIP_MEMORY_SCOPE_WORKGROUP);

        if (tt + 1 < NT) {
            // my tile-(tt+1) DMAs: by now they had a full MFMA block to land
            __builtin_amdgcn_s_waitcnt(0x0F70);  // vmcnt(0)
            if (sig) __hip_atomic_fetch_add(&flags[q], 1u, __ATOMIC_RELEASE, __HIP_MEMORY_SCOPE_WORKGROUP);
        }
    }

    const float scale = pa[0] * pb[0];
    const int col = lane & 31;
    const int rbase = (lane >> 5) * 4;
#pragma unroll
    for (int i = 0; i < 2; ++i)
#pragma unroll
        for (int j = 0; j < 2; ++j)
#pragma unroll
            for (int r = 0; r < 16; ++r) {
                const int rowf = rbase + (r & 3) + 8 * (r >> 2);
                float v = (float)acc[i][j][r] * scale;
                v = rintf(v);
                v = fminf(127.f, fmaxf(-128.f, v));
                out[(size_t)(m0 + wm + i * 32 + rowf) * N_DIM +
                    (n0 + wn + j * 32 + col)] = (int)v;
            }
}

extern "C" void kernel_launch(void* const* d_in, const int* in_sizes, int n_in,
                              void* d_out, int out_size, void* d_ws, size_t ws_size,
                              hipStream_t stream) {
    const int* x = (const int*)d_in[0];
    const int* w = (const int*)d_in[1];
    const float* pa = (const float*)d_in[2];
    const float* pb = (const float*)d_in[3];
    int* out = (int*)d_out;

    int8_t* a8 = (int8_t*)d_ws;                       // 32 MiB
    int8_t* bt8 = a8 + (size_t)M_DIM * K_DIM;         // 16 MiB

    const int nwords_a = M_DIM * K_DIM / 16;
    pack_a_perm<<<nwords_a / 256, 256, 0, stream>>>(x, (uint4v*)a8);
    transpose_b_perm<<<dim3(N_DIM / 64, K_DIM / 64), 256, 0, stream>>>(w, bt8);
    gemm_kernel<<<dim3(N_DIM / 128, M_DIM / 128), 256, 0, stream>>>(a8, bt8, pa, pb, out);
}